// Round 9
// baseline (1686.919 us; speedup 1.0000x reference)
//
#include <hip/hip_runtime.h>
#include <math.h>

// Problem constants
#define NB 4
#define NL 1024
#define NDT 897      // d_token
#define NH 8
#define NDQ 512      // d_qk per head
#define NDV 768      // d_v
#define NTOP 8
#define NCAND 16
#define KP 928       // K padded to 29*32 (zero-filled beyond 897)
#define SCALE 0.044194173824159216  // 1/sqrt(512)

typedef unsigned short ushort_t;
typedef __attribute__((ext_vector_type(8))) short short8;
typedef __attribute__((ext_vector_type(4))) float f32x4;

// fp32 -> bf16 RNE
static __device__ __forceinline__ ushort_t f2bf(float f) {
    unsigned u = __float_as_uint(f);
    unsigned r = (u + 0x7fffu + ((u >> 16) & 1u)) >> 16;
    return (ushort_t)r;
}
static __device__ __forceinline__ float bf2f(ushort_t u) {
    return __uint_as_float((unsigned)u << 16);
}
// 3-way bf16 split: x ~= b1+b2+b3 with error ~2^-27|x|
static __device__ __forceinline__ void split3(float x, ushort_t& b1, ushort_t& b2, ushort_t& b3) {
    b1 = f2bf(x);
    float r1 = x - bf2f(b1);
    b2 = f2bf(r1);
    float r2 = r1 - bf2f(b2);
    b3 = f2bf(r2);
}
// 2-way bf16 split: x ~= b1+b2 with error ~2^-18|x|
static __device__ __forceinline__ void split2(float x, ushort_t& b1, ushort_t& b2) {
    b1 = f2bf(x);
    b2 = f2bf(x - bf2f(b1));
}

// ---------------------------------------------------------------------------
// One-time: W[897][4096] -> transposed 3-plane bf16 wsp[src][3][4096][928]
// ---------------------------------------------------------------------------
__global__ __launch_bounds__(256)
void split_w(const float* __restrict__ w_qs, const float* __restrict__ w_ks,
             ushort_t* __restrict__ wsp)
{
    const float* W = (blockIdx.z == 0) ? w_qs : w_ks;
    ushort_t* dst = wsp + (size_t)blockIdx.z * 3 * 4096 * KP;
    const int n0 = blockIdx.x * 64;
    const int k0 = blockIdx.y * 32;
    __shared__ float tf[32][65];
    const int t = threadIdx.x;
#pragma unroll
    for (int it = 0; it < 8; it++) {
        int kk = it * 4 + (t >> 6);
        int nn = t & 63;
        int kg = k0 + kk;
        tf[kk][nn] = (kg < NDT) ? W[(size_t)kg * 4096 + n0 + nn] : 0.f;
    }
    __syncthreads();
    const int nn = t >> 2;     // 0..63
    const int oct = t & 3;     // k-octet within the 32-k tile
    ushort_t o[3][8];
#pragma unroll
    for (int j = 0; j < 8; j++) {
        float x = tf[oct * 8 + j][nn];
        split3(x, o[0][j], o[1][j], o[2][j]);
    }
#pragma unroll
    for (int p = 0; p < 3; p++)
        *(uint4*)(dst + ((size_t)p * 4096 + n0 + nn) * KP + k0 + oct * 8) = *(const uint4*)o[p];
}

// ---------------------------------------------------------------------------
// One-time: w_vs[768][6144] -> per-head 2-plane bf16 wvs2[p][h][dk][768k]
// ---------------------------------------------------------------------------
__global__ __launch_bounds__(256)
void split_wvs(const float* __restrict__ w_vs, ushort_t* __restrict__ wvs2)
{
    int gid8 = ((int)blockIdx.x * 256 + threadIdx.x) * 8;   // < 4,718,592
    int dk  = gid8 / 6144;
    int rem = gid8 % 6144;
    int h   = rem / 768;
    int kk  = rem % 768;
    const float* src = w_vs + (size_t)dk * 6144 + rem;
    ushort_t o[2][8];
#pragma unroll
    for (int j = 0; j < 8; j++) split2(src[j], o[0][j], o[1][j]);
#pragma unroll
    for (int p = 0; p < 2; p++)
        *(uint4*)(wvs2 + ((size_t)(p * 8 + h) * 768 + dk) * 768 + kk) = *(const uint4*)o[p];
}

// ---------------------------------------------------------------------------
// One-time: w_fc[6144][768] -> transposed per-head 2-plane bf16
// wfcT2[p][h][dv][768k]. LDS 32k x 64dv transpose tile.
// ---------------------------------------------------------------------------
__global__ __launch_bounds__(256)
void split_wfcT(const float* __restrict__ w_fc, ushort_t* __restrict__ wfcT2)
{
    const int dv0 = blockIdx.x * 64;
    const int kg0 = blockIdx.y * 32;     // 768%32==0 -> never crosses heads
    __shared__ float tf[32][65];
    const int t = threadIdx.x;
#pragma unroll
    for (int it = 0; it < 8; it++) {
        int kk = it * 4 + (t >> 6);
        int dd = t & 63;
        tf[kk][dd] = w_fc[(size_t)(kg0 + kk) * 768 + dv0 + dd];
    }
    __syncthreads();
    const int dv = t >> 2;
    const int oct = t & 3;
    const int h  = kg0 / 768;
    const int kl = kg0 % 768;
    ushort_t o[2][8];
#pragma unroll
    for (int j = 0; j < 8; j++) split2(tf[oct * 8 + j][dv], o[0][j], o[1][j]);
#pragma unroll
    for (int p = 0; p < 2; p++)
        *(uint4*)(wfcT2 + ((size_t)(p * 8 + h) * 768 + dv0 + dv) * 768 + kl + oct * 8) = *(const uint4*)o[p];
}

// ---------------------------------------------------------------------------
// combine via 2-way split bf16 MFMA (round 16, HW-proven).
// ---------------------------------------------------------------------------
__global__ __launch_bounds__(256)
void combine_mfma(const ushort_t* __restrict__ wfcT2, const ushort_t* __restrict__ wvs2,
                  ushort_t* __restrict__ MhTb)
{
    const int h = blockIdx.z;
    const int n0 = blockIdx.x * 128, m0 = blockIdx.y * 128;
    __shared__ ushort_t Al[2 * 5120];
    __shared__ ushort_t Bl[2 * 5120];
    const int t = threadIdx.x;
    const int lane = t & 63, wv = t >> 6;
    const int quad = lane >> 4, l16 = lane & 15;

    f32x4 acc[2][8];
#pragma unroll
    for (int i = 0; i < 2; i++)
#pragma unroll
        for (int j = 0; j < 8; j++) acc[i][j] = (f32x4){0.f, 0.f, 0.f, 0.f};

    for (int kc = 0; kc < 768; kc += 32) {
#pragma unroll
        for (int p = 0; p < 2; p++) {
            const ushort_t* Ap = wfcT2 + (size_t)(p * 8 + h) * 768 * 768;
            const ushort_t* Bp = wvs2  + (size_t)(p * 8 + h) * 768 * 768;
#pragma unroll
            for (int pp = 0; pp < 2; pp++) {
                int c = t + pp * 256;
                int r = c >> 2, ck = c & 3;
                int pc = (ck + ((r + (r >> 3)) & 3)) & 3;
                uint4 va = *(const uint4*)(Ap + (size_t)(m0 + r) * 768 + kc + ck * 8);
                *(uint4*)&Al[p * 5120 + r * 40 + pc * 8] = va;
                uint4 vb = *(const uint4*)(Bp + (size_t)(n0 + r) * 768 + kc + ck * 8);
                *(uint4*)&Bl[p * 5120 + r * 40 + pc * 8] = vb;
            }
        }
        __syncthreads();

        short8 af[2][2], bf[2][8];
#pragma unroll
        for (int p = 0; p < 2; p++) {
#pragma unroll
            for (int i = 0; i < 2; i++) {
                int r = wv * 32 + i * 16 + l16;
                int pc = (quad + ((r + (r >> 3)) & 3)) & 3;
                af[p][i] = *(const short8*)&Al[p * 5120 + r * 40 + pc * 8];
            }
#pragma unroll
            for (int j = 0; j < 8; j++) {
                int r = j * 16 + l16;
                int pc = (quad + ((r + (r >> 3)) & 3)) & 3;
                bf[p][j] = *(const short8*)&Bl[p * 5120 + r * 40 + pc * 8];
            }
        }
#pragma unroll
        for (int i = 0; i < 2; i++)
#pragma unroll
            for (int j = 0; j < 8; j++) {
                acc[i][j] = __builtin_amdgcn_mfma_f32_16x16x32_bf16(af[0][i], bf[0][j], acc[i][j], 0, 0, 0);
                acc[i][j] = __builtin_amdgcn_mfma_f32_16x16x32_bf16(af[0][i], bf[1][j], acc[i][j], 0, 0, 0);
                acc[i][j] = __builtin_amdgcn_mfma_f32_16x16x32_bf16(af[1][i], bf[0][j], acc[i][j], 0, 0, 0);
            }
        __syncthreads();
    }

#pragma unroll
    for (int i = 0; i < 2; i++)
#pragma unroll
        for (int j = 0; j < 8; j++) {
            int gn = n0 + j * 16 + l16;                        // dk
#pragma unroll
            for (int reg = 0; reg < 4; reg++) {
                int gm = m0 + wv * 32 + i * 16 + quad * 4 + reg;   // dv
                MhTb[((size_t)h * NDV + gm) * NDV + gn] = f2bf(acc[i][j][reg]);
            }
        }
}

// ---------------------------------------------------------------------------
// Per batch: A rows (q,k)[1024][897] -> 3-plane bf16 asp[src][3][1024][928]
// ---------------------------------------------------------------------------
__global__ __launch_bounds__(256)
void split_a(const float* __restrict__ q, const float* __restrict__ k,
             ushort_t* __restrict__ asp, int b)
{
    const int row = blockIdx.x;
    const int z = blockIdx.y;
    const float* A = (z == 0 ? q : k) + ((size_t)b * NL + row) * NDT;
    ushort_t* dst = asp + (size_t)z * 3 * 1024 * KP;
    const int t = threadIdx.x;
    if (t >= 232) return;               // 232*4 = 928
    const int kb = t * 4;
    ushort_t o[3][4];
#pragma unroll
    for (int j = 0; j < 4; j++) {
        int kk = kb + j;
        float x = (kk < NDT) ? A[kk] : 0.f;
        split3(x, o[0][j], o[1][j], o[2][j]);
    }
#pragma unroll
    for (int p = 0; p < 3; p++)
        *(uint2*)(dst + ((size_t)p * 1024 + row) * KP + kb) = *(const uint2*)o[p];
}

// ---------------------------------------------------------------------------
// proj: C[1024x4096] = A[1024x897] @ W[897x4096] via 3-way split-bf16,
// 6-pass 16x16x32 MFMA (round 15, HW-proven).
// ---------------------------------------------------------------------------
__global__ __launch_bounds__(256)
void proj_qk_mfma6(const ushort_t* __restrict__ asp, const ushort_t* __restrict__ wsp,
                   float* __restrict__ qh32, float* __restrict__ kh32,
                   ushort_t* __restrict__ qhb, ushort_t* __restrict__ khb)
{
    const int z = blockIdx.z;
    const int n0 = blockIdx.x * 128, m0 = blockIdx.y * 128;
    float*    C32 = z == 0 ? qh32 : kh32;
    ushort_t* Cb  = z == 0 ? qhb  : khb;
    const ushort_t* Ab = asp + (size_t)z * 3 * 1024 * KP;
    const ushort_t* Bb = wsp + (size_t)z * 3 * 4096 * KP;

    __shared__ ushort_t Al[3 * 128 * 40];
    __shared__ ushort_t Bl[3 * 128 * 40];
    const int t = threadIdx.x;
    const int lane = t & 63, wv = t >> 6;
    const int quad = lane >> 4, l16 = lane & 15;

    f32x4 acc[2][8];
#pragma unroll
    for (int i = 0; i < 2; i++)
#pragma unroll
        for (int j = 0; j < 8; j++) acc[i][j] = (f32x4){0.f, 0.f, 0.f, 0.f};

    for (int kc = 0; kc < KP; kc += 32) {
#pragma unroll
        for (int p = 0; p < 3; p++) {
            const ushort_t* Ap = Ab + (size_t)p * 1024 * KP;
            const ushort_t* Bp = Bb + (size_t)p * 4096 * KP;
#pragma unroll
            for (int pp = 0; pp < 2; pp++) {
                int c = t + pp * 256;
                int r = c >> 2, ck = c & 3;
                int pc = (ck + ((r + (r >> 3)) & 3)) & 3;
                uint4 va = *(const uint4*)(Ap + (size_t)(m0 + r) * KP + kc + ck * 8);
                *(uint4*)&Al[p * 5120 + r * 40 + pc * 8] = va;
                uint4 vb = *(const uint4*)(Bp + (size_t)(n0 + r) * KP + kc + ck * 8);
                *(uint4*)&Bl[p * 5120 + r * 40 + pc * 8] = vb;
            }
        }
        __syncthreads();

        short8 af[3][2], bf[3][8];
#pragma unroll
        for (int p = 0; p < 3; p++) {
#pragma unroll
            for (int i = 0; i < 2; i++) {
                int r = wv * 32 + i * 16 + l16;
                int pc = (quad + ((r + (r >> 3)) & 3)) & 3;
                af[p][i] = *(const short8*)&Al[p * 5120 + r * 40 + pc * 8];
            }
#pragma unroll
            for (int j = 0; j < 8; j++) {
                int r = j * 16 + l16;
                int pc = (quad + ((r + (r >> 3)) & 3)) & 3;
                bf[p][j] = *(const short8*)&Bl[p * 5120 + r * 40 + pc * 8];
            }
        }
#pragma unroll
        for (int i = 0; i < 2; i++)
#pragma unroll
            for (int j = 0; j < 8; j++) {
                acc[i][j] = __builtin_amdgcn_mfma_f32_16x16x32_bf16(af[0][i], bf[0][j], acc[i][j], 0, 0, 0);
                acc[i][j] = __builtin_amdgcn_mfma_f32_16x16x32_bf16(af[0][i], bf[1][j], acc[i][j], 0, 0, 0);
                acc[i][j] = __builtin_amdgcn_mfma_f32_16x16x32_bf16(af[1][i], bf[0][j], acc[i][j], 0, 0, 0);
                acc[i][j] = __builtin_amdgcn_mfma_f32_16x16x32_bf16(af[0][i], bf[2][j], acc[i][j], 0, 0, 0);
                acc[i][j] = __builtin_amdgcn_mfma_f32_16x16x32_bf16(af[1][i], bf[1][j], acc[i][j], 0, 0, 0);
                acc[i][j] = __builtin_amdgcn_mfma_f32_16x16x32_bf16(af[2][i], bf[0][j], acc[i][j], 0, 0, 0);
            }
        __syncthreads();
    }

#pragma unroll
    for (int i = 0; i < 2; i++)
#pragma unroll
        for (int j = 0; j < 8; j++) {
            int gn = n0 + j * 16 + l16;
#pragma unroll
            for (int reg = 0; reg < 4; reg++) {
                int gm = m0 + wv * 32 + i * 16 + quad * 4 + reg;
                float vv = acc[i][j][reg];
                C32[(size_t)gm * 4096 + gn] = vv;
                Cb[(size_t)gm * 4096 + gn] = f2bf(vv);
            }
        }
}

// ---------------------------------------------------------------------------
// Round-17: scores + FUSED chunk-local top-16. Scores stay in registers —
// the 33.5MB score slab write/read/zero round-trip is eliminated (attn output
// = one memset + sparse scatter in select_rescore). Per 16-lane quad-group
// (one row's 128 cols): 16 iters of {7-compare scan over 8 regs + 4-step
// xor-shfl(1,2,4,8) argmax (intra-quad)} -> candv/candi[row][chunk][16].
// Tie-break lower global column at every stage == old select's semantics ->
// IDENTICAL candidate set -> bit-identical final output.
// ---------------------------------------------------------------------------
__global__ __launch_bounds__(256)
void scores_cand(const ushort_t* __restrict__ qhb, const ushort_t* __restrict__ khb,
                 const float* __restrict__ kmask,
                 float* __restrict__ candv, int* __restrict__ candi, int b)
{
    const int h = blockIdx.z;
    const int n0 = blockIdx.x * 128, m0 = blockIdx.y * 128;
    const int bx = blockIdx.x;
    __shared__ ushort_t Al[128 * 40];
    __shared__ ushort_t Bl[128 * 40];
    const int t = threadIdx.x;
    const int lane = t & 63, wv = t >> 6;
    const int quad = lane >> 4, l16 = lane & 15;

    f32x4 acc[2][8];
#pragma unroll
    for (int i = 0; i < 2; i++)
#pragma unroll
        for (int j = 0; j < 8; j++) acc[i][j] = (f32x4){0.f, 0.f, 0.f, 0.f};

    const ushort_t* Ag = qhb + (size_t)h * NDQ;
    const ushort_t* Bg = khb + (size_t)h * NDQ;

    for (int kc = 0; kc < NDQ; kc += 32) {
#pragma unroll
        for (int p = 0; p < 2; p++) {
            int c = t + p * 256;
            int r = c >> 2, ck = c & 3;
            int pc = (ck + ((r + (r >> 3)) & 3)) & 3;
            uint4 va = *(const uint4*)(Ag + (size_t)(m0 + r) * 4096 + kc + ck * 8);
            *(uint4*)&Al[r * 40 + pc * 8] = va;
        }
#pragma unroll
        for (int p = 0; p < 2; p++) {
            int c = t + p * 256;
            int r = c >> 2, ck = c & 3;
            int pc = (ck + ((r + (r >> 3)) & 3)) & 3;
            uint4 vb = *(const uint4*)(Bg + (size_t)(n0 + r) * 4096 + kc + ck * 8);
            *(uint4*)&Bl[r * 40 + pc * 8] = vb;
        }
        __syncthreads();

        short8 af[2], bf[8];
#pragma unroll
        for (int i = 0; i < 2; i++) {
            int r = wv * 32 + i * 16 + l16;
            int pc = (quad + ((r + (r >> 3)) & 3)) & 3;
            af[i] = *(const short8*)&Al[r * 40 + pc * 8];
        }
#pragma unroll
        for (int j = 0; j < 8; j++) {
            int r = j * 16 + l16;
            int pc = (quad + ((r + (r >> 3)) & 3)) & 3;
            bf[j] = *(const short8*)&Bl[r * 40 + pc * 8];
        }
#pragma unroll
        for (int i = 0; i < 2; i++)
#pragma unroll
            for (int j = 0; j < 8; j++)
                acc[i][j] = __builtin_amdgcn_mfma_f32_16x16x32_bf16(af[i], bf[j], acc[i][j], 0, 0, 0);
        __syncthreads();
    }

    // fold scale + kmask + diag into acc (same arithmetic as old store path)
    const float scl = (float)SCALE;
#pragma unroll
    for (int i = 0; i < 2; i++)
#pragma unroll
        for (int j = 0; j < 8; j++) {
            int gn = n0 + j * 16 + l16;
            float km = kmask[b * NL + gn];
#pragma unroll
            for (int reg = 0; reg < 4; reg++) {
                int gm = m0 + wv * 32 + i * 16 + quad * 4 + reg;
                float s = acc[i][j][reg] * scl + km;
                if (gm == gn) s -= 10000.0f;   // qk_mask = -1e4 * I
                acc[i][j][reg] = s;
            }
        }

    // chunk-local top-16 per row (one row per quad-group per slot)
#pragma unroll
    for (int slot = 0; slot < 8; slot++) {
        const int i = slot >> 2, reg = slot & 3;
        const int gr = m0 + wv * 32 + i * 16 + quad * 4 + reg;
        float vv[8];
#pragma unroll
        for (int j = 0; j < 8; j++) vv[j] = acc[i][j][reg];
        for (int it = 0; it < 16; it++) {
            float bv = vv[0]; int bj = 0;
#pragma unroll
            for (int j = 1; j < 8; j++)
                if (vv[j] > bv) { bv = vv[j]; bj = j; }
            int bc = bj * 16 + l16;                 // col within 128-chunk
#pragma unroll
            for (int s = 1; s < 16; s <<= 1) {      // intra-quad butterfly
                float ov = __shfl_xor(bv, s);
                int   oc = __shfl_xor(bc, s);
                if (ov > bv || (ov == bv && oc < bc)) { bv = ov; bc = oc; }
            }
            if (l16 == it) {
                size_t o = (((size_t)h * NL + gr) * 8 + bx) * 16 + it;
                candv[o] = bv;
                candi[o] = n0 + bc;
            }
            int wj = bc >> 4, wl = bc & 15;
            if (l16 == wl) {
#pragma unroll
                for (int j = 0; j < 8; j++)
                    if (j == wj) vv[j] = -3.0e38f;
            }
        }
    }
}

// ---------------------------------------------------------------------------
// Round-17 select: merge 128 pre-selected candidates -> top-16 (2-reg scan +
// 6-step butterfly; winner masked by unique index), then the verbatim f64
// rescore / exact top-8 / softmax. Scatter into PRE-ZEROED attn (memset) —
// no row zeroing, no fence. Candidate set identical to old full-row scan.
// ---------------------------------------------------------------------------
__global__ __launch_bounds__(256)
void select_rescore(const float* __restrict__ candv, const int* __restrict__ candi,
                    const float* __restrict__ qh32, const float* __restrict__ kh32,
                    const float* __restrict__ kmask, float* __restrict__ attn,
                    float* __restrict__ topw, int* __restrict__ topi, int b)
{
    const int lane = threadIdx.x & 63;
    const int w = threadIdx.x >> 6;
    const int r = blockIdx.x * 4 + w;        // h*1024 + q
    const int q = r & 1023, h = r >> 10;

    float cv[2]; int ci[2];
    {
        size_t base = (size_t)r * 128 + lane * 2;
        cv[0] = candv[base];     cv[1] = candv[base + 1];
        ci[0] = candi[base];     ci[1] = candi[base + 1];
    }

    int cidx[NCAND];
    for (int tsel = 0; tsel < NCAND; tsel++) {
        float bv = cv[0]; int bi = ci[0];
        if (cv[1] > bv || (cv[1] == bv && ci[1] < bi)) { bv = cv[1]; bi = ci[1]; }
#pragma unroll
        for (int s = 1; s < 64; s <<= 1) {
            float ov = __shfl_xor(bv, s);
            int   oi = __shfl_xor(bi, s);
            if (ov > bv || (ov == bv && oi < bi)) { bv = ov; bi = oi; }
        }
        cidx[tsel] = bi;
        if (ci[0] == bi) cv[0] = -3.0e38f;   // indices unique per row
        if (ci[1] == bi) cv[1] = -3.0e38f;
    }

    // f64 rescore of the 16 candidates from f32-stored projections (verbatim)
    const float* qrow  = qh32 + (size_t)q * 4096 + h * NDQ;
    const float* kbase = kh32 + h * NDQ;
    double qd[8];
#pragma unroll
    for (int j = 0; j < 8; j++) qd[j] = (double)qrow[lane + 64 * j];

    double sv[NCAND]; int si[NCAND];
#pragma unroll
    for (int c = 0; c < NCAND; c++) {
        int idx = cidx[c];
        const float* krow = kbase + (size_t)idx * 4096;
        double s = 0.0;
#pragma unroll
        for (int j = 0; j < 8; j++) s = fma(qd[j], (double)krow[lane + 64 * j], s);
#pragma unroll
        for (int sh = 1; sh < 64; sh <<= 1) s += __shfl_xor(s, sh);
        s = s * SCALE + (double)kmask[b * NL + idx];
        if (idx == q) s -= 10000.0;
        sv[c] = s; si[c] = idx;
    }
    // exact top-8, ties -> lower index (lax.top_k semantics)
    double vs[NTOP]; int is_[NTOP];
    unsigned used = 0;
#pragma unroll
    for (int tsel = 0; tsel < NTOP; tsel++) {
        double bv = -1.0e300; int bi = 1 << 30; int bc = 0;
#pragma unroll
        for (int c = 0; c < NCAND; c++) {
            bool free_c = !(used & (1u << c));
            bool better = free_c && (sv[c] > bv || (sv[c] == bv && si[c] < bi));
            if (better) { bv = sv[c]; bi = si[c]; bc = c; }
        }
        used |= (1u << bc);
        vs[tsel] = bv; is_[tsel] = bi;
    }
    double m = vs[0];
    double e[NTOP], Z = 0.0;
#pragma unroll
    for (int i = 0; i < NTOP; i++) { e[i] = exp(vs[i] - m); Z += e[i]; }

    if (lane == 0) {
        float* row = attn + (size_t)r * NL;   // pre-zeroed by memset
#pragma unroll
        for (int i = 0; i < NTOP; i++) {
            float wv = (float)(e[i] / Z);
            topw[(size_t)r * NTOP + i] = wv;
            topi[(size_t)r * NTOP + i] = is_[i];
            row[is_[i]] = wv;
        }
    }
}

// ---------------------------------------------------------------------------
// v -> bf16 (all batches at once)
// ---------------------------------------------------------------------------
__global__ __launch_bounds__(256)
void conv_v_bf16(const float* __restrict__ v, ushort_t* __restrict__ vb)
{
    size_t i = ((size_t)blockIdx.x * 256 + threadIdx.x) * 4;
    float4 f = *(const float4*)(v + i);
    ushort_t o[4] = { f2bf(f.x), f2bf(f.y), f2bf(f.z), f2bf(f.w) };
    *(uint2*)(vb + i) = *(uint2*)o;
}

// ---------------------------------------------------------------------------
// vw[h,l,:] = vb16[b,l,:] @ MhT[h]^T  via bf16 MFMA (unchanged)
// ---------------------------------------------------------------------------
__global__ __launch_bounds__(256)
void vw_mfma(const ushort_t* __restrict__ vb, const ushort_t* __restrict__ MhTb,
             float* __restrict__ vw, int b)
{
    const int h = blockIdx.z;
    const int n0 = blockIdx.x * 128, m0 = blockIdx.y * 128;
    __shared__ ushort_t Al[128 * 40];
    __shared__ ushort_t Bl[128 * 40];
    const int t = threadIdx.x;
    const int lane = t & 63, wv = t >> 6;
    const int quad = lane >> 4, l16 = lane & 15;

    f32x4 acc[2][8];
#pragma unroll
    for (int i = 0; i < 2; i++)
#pragma unroll
        for (int j = 0; j < 8; j++) acc[i][j] = (f32x4){0.f, 0.f, 0.f, 0.f};

    const ushort_t* Ag = vb + (size_t)b * NL * NDV;     // [m][k], stride 768
    const ushort_t* Bg = MhTb + (size_t)h * NDV * NDV;  // [n][k], stride 768

    for (int kc = 0; kc < NDV; kc += 32) {
#pragma unroll
        for (int p = 0; p < 2; p++) {
            int c = t + p * 256;
            int r = c >> 2, ck = c & 3;
            int pc = (ck + ((r + (r >> 3)) & 3)) & 3;
            uint4 va = *(const uint4*)(Ag + (size_t)(m0 + r) * NDV + kc + ck * 8);
            *(uint4*)&Al[r * 40 + pc * 8] = va;
        }
#pragma unroll
        for (int p = 0; p < 2; p++) {
            int c = t + p * 256;
            int r = c >> 2, ck = c & 3;
            int pc = (ck + ((r + (r >> 3)) & 3)) & 3;
            uint4 vv = *(const uint4*)(Bg + (size_t)(n0 + r) * NDV + kc + ck * 8);
            *(uint4*)&Bl[r * 40 + pc * 8] = vv;
        }
        __syncthreads();

        short8 af[2], bf[8];
#pragma unroll
        for (int i = 0; i < 2; i++) {
            int r = wv * 32 + i * 16 + l16;
            int pc = (quad + ((r + (r >> 3)) & 3)) & 3;
            af[i] = *(const short8*)&Al[r * 40 + pc * 8];
        }
#pragma unroll
        for (int j = 0; j < 8; j++) {
            int r = j * 16 + l16;
            int pc = (quad + ((r + (r >> 3)) & 3)) & 3;
            bf[j] = *(const short8*)&Bl[r * 40 + pc * 8];
        }
#pragma unroll
        for (int i = 0; i < 2; i++)
#pragma unroll
            for (int j = 0; j < 8; j++)
                acc[i][j] = __builtin_amdgcn_mfma_f32_16x16x32_bf16(af[i], bf[j], acc[i][j], 0, 0, 0);
        __syncthreads();
    }

#pragma unroll
    for (int i = 0; i < 2; i++) {
#pragma unroll
        for (int j = 0; j < 8; j++) {
            int gn = n0 + j * 16 + l16;
#pragma unroll
            for (int reg = 0; reg < 4; reg++) {
                int gm = m0 + wv * 32 + i * 16 + quad * 4 + reg;
                vw[((size_t)h * NL + gm) * NDV + gn] = acc[i][j][reg];
            }
        }
    }
}

// ---------------------------------------------------------------------------
// out[b,q,:] = sum_{h,i} w[h,q,i] * vw[h, idx[h,q,i], :]   (one block per q)
// ---------------------------------------------------------------------------
__global__ __launch_bounds__(256)
void gather_out(const float* __restrict__ vw, const float* __restrict__ topw,
                const int* __restrict__ topi, float* __restrict__ out, int b)
{
    const int q = blockIdx.x;
    __shared__ float sw[64];
    __shared__ int   sidx[64];
    const int t = threadIdx.x;
    if (t < 64) {
        int h = t >> 3, i = t & 7;
        size_t rr = ((size_t)h * NL + q) * NTOP + i;
        sw[t]   = topw[rr];
        sidx[t] = topi[rr] + h * NL;   // row into vw [8*1024, 768]
    }
    __syncthreads();
    float* orow = out + (size_t)(b * NL + q) * NDV;
    for (int dv = t; dv < NDV; dv += 256) {
        float acc = 0.f;
#pragma unroll
        for (int j = 0; j < 64; j++)
            acc = fmaf(sw[j], vw[(size_t)sidx[j] * NDV + dv], acc);
        orow[dv] = acc;
    }
}

// ---------------------------------------------------------------------------
extern "C" void kernel_launch(void* const* d_in, const int* in_sizes, int n_in,
                              void* d_out, int out_size, void* d_ws, size_t ws_size,
                              hipStream_t stream)
{
    const float* q     = (const float*)d_in[0];
    const float* k     = (const float*)d_in[1];
    const float* v     = (const float*)d_in[2];
    // d_in[3] = qk_mask (-1e4 * I), applied analytically
    const float* kmask = (const float*)d_in[4];
    const float* w_qs  = (const float*)d_in[5];
    const float* w_ks  = (const float*)d_in[6];
    const float* w_vs  = (const float*)d_in[7];
    const float* w_fc  = (const float*)d_in[8];

    // workspace layout (123.6 MB <= proven 125.3 MB):
    char* ws = (char*)d_ws;
    float*    qh32 = (float*)   (ws + 0);             // 16,777,216
    float*    kh32 = (float*)   (ws + 16777216);      // 16,777,216
    ushort_t* qhb  = (ushort_t*)(ws + 33554432);      //  8,388,608
    ushort_t* khb  = (ushort_t*)(ws + 41943040);      //  8,388,608
    ushort_t* MhTb = (ushort_t*)(ws + 50331648);      //  9,437,184
    ushort_t* vb16 = (ushort_t*)(ws + 59768832);      //  6,291,456
    float*    topw = (float*)   (ws + 66060288);      //    262,144
    int*      topi = (int*)     (ws + 66322432);      //    262,144
    ushort_t* wsp  = (ushort_t*)(ws + 66584576);      // 45,613,056 (end 112,197,632)
    ushort_t* asp  = (ushort_t*)(ws + 112197632);     // 11,403,264 (end 123,600,896)
    // vw ALIASES qh32+kh32 (25.2MB <= 33.6MB): select(b) reads qh32/kh32
    // before vw_mfma(b) writes; gather(b) before proj(b+1).
    float*    vw   = (float*)   (ws + 0);
    // combine split planes ALIAS wsp (consumed before split_w overwrites).
    ushort_t* wfcT2 = (ushort_t*)(ws + 66584576);            // 18,874,368
    ushort_t* wvs2  = (ushort_t*)(ws + 66584576 + 18874368); // 18,874,368
    // candidate lists ALIAS asp (asp consumed by proj before scores_cand
    // writes; cand consumed by select before next batch's split_a).
    float* candv = (float*)(ws + 112197632);          // 4,194,304
    int*   candi = (int*)  (ws + 116391936);          // 4,194,304

    float* out  = (float*)d_out;                      // [4,1024,768]
    float* attn = out + (size_t)NB * NL * NDV;        // [4,8,1024,1024]

    // attn = zeros + sparse scatter (scores never materialized)
    hipMemsetAsync(attn, 0, (size_t)NB * NH * NL * NL * sizeof(float), stream);

    split_wvs   <<<2304, 256, 0, stream>>>(w_vs, wvs2);
    split_wfcT  <<<dim3(12, 192), 256, 0, stream>>>(w_fc, wfcT2);
    combine_mfma<<<dim3(6, 6, 8), 256, 0, stream>>>(wfcT2, wvs2, MhTb);
    split_w     <<<dim3(64, 29, 2), 256, 0, stream>>>(w_qs, w_ks, wsp);   // overwrites split planes
    conv_v_bf16 <<<3072, 256, 0, stream>>>(v, vb16);

    for (int b = 0; b < NB; b++) {
        float* slab = attn + (size_t)b * NH * NL * NL;   // final attn (pre-zeroed)

        split_a       <<<dim3(1024, 2), 256, 0, stream>>>(q, k, asp, b);
        proj_qk_mfma6 <<<dim3(32, 8, 2), 256, 0, stream>>>(asp, wsp, qh32, kh32, qhb, khb);
        scores_cand   <<<dim3(8, 8, 8), 256, 0, stream>>>(qhb, khb, kmask, candv, candi, b);
        select_rescore<<<2048, 256, 0, stream>>>(candv, candi, qh32, kh32, kmask,
                                                 slab, topw, topi, b);
        vw_mfma       <<<dim3(6, 8, 8), 256, 0, stream>>>(vb16, MhTb, vw, b);
        gather_out    <<<NL, 256, 0, stream>>>(vw, topw, topi, out, b);
    }
}